// Round 1
// baseline (125.779 us; speedup 1.0000x reference)
//
#include <hip/hip_runtime.h>
#include <hip/hip_bf16.h>

// Problem constants
#define B 8
#define LQ 64
#define LK 512
#define E_DIM 32
#define H_N 2
#define DIM 128
#define LAT 64
#define DK 16   // E/H

// ------------------------------------------------------------------
// K1: q/k projections.  qp[b,i,j] = bq[j] + sum_t query[b,i,t]*Wq[t,j]
// Rows 0..511 are query rows (8*64), rows 512..4607 are key rows (8*512).
// 144 blocks x 256 threads, 32 rows/block.
// ------------------------------------------------------------------
__global__ __launch_bounds__(256) void proj_kernel(
    const float* __restrict__ query, const float* __restrict__ key,
    const float* __restrict__ Wq, const float* __restrict__ bq,
    const float* __restrict__ Wk, const float* __restrict__ bk,
    float* __restrict__ qp, float* __restrict__ kp) {
  __shared__ float Wl[32 * 33];
  __shared__ float bl[32];
  __shared__ float inl[32 * 33];
  const int blk = blockIdx.x;
  const int row0 = blk * 32;
  const bool isQ = row0 < 512;
  const float* W = isQ ? Wq : Wk;
  const float* bias = isQ ? bq : bk;
  const float* in = isQ ? query : key;
  float* outp = isQ ? qp : kp;
  const int inRowBase = isQ ? row0 : (row0 - 512);
  const int tid = threadIdx.x;

  for (int i = tid; i < 1024; i += 256) Wl[(i / 32) * 33 + (i % 32)] = W[i];
  if (tid < 32) bl[tid] = bias[tid];
  for (int i = tid; i < 1024; i += 256)
    inl[(i / 32) * 33 + (i % 32)] = in[inRowBase * 32 + i];
  __syncthreads();

  const int col = tid % 32;  // lanes consecutive in col -> coalesced out
  const int rg = tid / 32;   // 0..7
#pragma unroll
  for (int rr = 0; rr < 4; ++rr) {
    const int rloc = rg * 4 + rr;
    float acc = bl[col];
#pragma unroll
    for (int t = 0; t < 32; ++t) acc += inl[rloc * 33 + t] * Wl[t * 33 + col];
    outp[(inRowBase + rloc) * 32 + col] = acc;
  }
}

// ------------------------------------------------------------------
// K2: scores + row-max + exp.  32 blocks (b*4 + h*2 + qt), 256 threads.
// Block computes S[32 x 512] for head h, q rows qt*32..+31, then
// e = exp(S - rowmax) -> e_ws[b,h,q,k].
// ------------------------------------------------------------------
__global__ __launch_bounds__(256) void score_kernel(
    const float* __restrict__ qp, const float* __restrict__ kp,
    float* __restrict__ e_ws) {
  const int blk = blockIdx.x;
  const int b = blk >> 2, h = (blk >> 1) & 1, qt = blk & 1;
  __shared__ float kt[512 * 20];   // [512][16] padded to 20 (bank-spread)
  __shared__ float qtl[32 * 20];
  const int tid = threadIdx.x;

  const float4* kp4 = (const float4*)kp;
  for (int i = tid; i < 2048; i += 256) {
    const int row = i >> 2, c4 = i & 3;
    float4 v = kp4[(b * 512 + row) * 8 + h * 4 + c4];
    *(float4*)&kt[row * 20 + c4 * 4] = v;
  }
  const float4* qp4 = (const float4*)qp;
  if (tid < 128) {
    const int row = tid >> 2, c4 = tid & 3;
    float4 v = qp4[(b * 64 + qt * 32 + row) * 8 + h * 4 + c4];
    *(float4*)&qtl[row * 20 + c4 * 4] = v;
  }
  __syncthreads();

  const int r = tid >> 3, kg = tid & 7;
  float qreg[16];
#pragma unroll
  for (int c4 = 0; c4 < 4; ++c4) {
    float4 v = *(const float4*)&qtl[r * 20 + c4 * 4];
    qreg[c4 * 4 + 0] = v.x; qreg[c4 * 4 + 1] = v.y;
    qreg[c4 * 4 + 2] = v.z; qreg[c4 * 4 + 3] = v.w;
  }
  float s[64];
#pragma unroll
  for (int j = 0; j < 64; ++j) {
    const int k = kg + (j << 3);
    float acc = 0.f;
#pragma unroll
    for (int c4 = 0; c4 < 4; ++c4) {
      float4 v = *(const float4*)&kt[k * 20 + c4 * 4];
      acc += qreg[c4 * 4 + 0] * v.x + qreg[c4 * 4 + 1] * v.y +
             qreg[c4 * 4 + 2] * v.z + qreg[c4 * 4 + 3] * v.w;
    }
    s[j] = acc * 0.25f;  // 1/sqrt(DK)
  }
  float m = -1e30f;
#pragma unroll
  for (int j = 0; j < 64; ++j) m = fmaxf(m, s[j]);
#pragma unroll
  for (int off = 1; off < 8; off <<= 1) m = fmaxf(m, __shfl_xor(m, off));

  float* erow = e_ws + ((size_t)((b * 2 + h) * 64 + qt * 32 + r)) * 512;
#pragma unroll
  for (int j = 0; j < 64; ++j) erow[kg + (j << 3)] = __expf(s[j] - m);
}

// ------------------------------------------------------------------
// K3: num/den GEMM + divide.  256 blocks (b*32 + rt*8 + ct), 256 threads.
// Block: E rows rt*32..+31 (hq index), channels ct*16..+15.
// num = E @ (mask*value), den = E @ mask; x = num/den ->
// x_ws[b, q, h*128 + c].
// ------------------------------------------------------------------
__global__ __launch_bounds__(256) void nd_kernel(
    const float* __restrict__ e_ws, const float* __restrict__ value,
    const int* __restrict__ mask, float* __restrict__ x_ws) {
  const int blk = blockIdx.x;
  const int b = blk >> 5, rt = (blk >> 3) & 3, ct = blk & 7;
  __shared__ float El[32 * 68];   // [32][64] pad->68
  __shared__ float nv[64 * 16];   // mask*value chunk
  __shared__ float nm[64 * 16];   // mask chunk
  const int tid = threadIdx.x;
  const int r = tid >> 3, cg = tid & 7;
  float n0 = 0.f, n1 = 0.f, d0 = 0.f, d1 = 0.f;
  const float4* value4 = (const float4*)value;
  const int4* mask4 = (const int4*)mask;

  for (int kc = 0; kc < 8; ++kc) {
    __syncthreads();
    // stage E tile: 32 rows x 64 k
    for (int i = tid; i < 512; i += 256) {
      const int row = i >> 4, kq = i & 15;
      float4 v = *(const float4*)&e_ws[(size_t)(b * 128 + rt * 32 + row) * 512 +
                                       kc * 64 + kq * 4];
      *(float4*)&El[row * 68 + kq * 4] = v;
    }
    // stage nv/nm: 64 k-rows x 16 channels
    {
      const int i = tid;  // exactly 256 float4 jobs
      const int krow = i >> 2, c4 = i & 3;
      const int gidx = ((b * 512 + kc * 64 + krow) * 128 + ct * 16 + c4 * 4) >> 2;
      float4 v = value4[gidx];
      int4 mm = mask4[gidx];
      float4 vv, mv;
      vv.x = mm.x ? v.x : 0.f; mv.x = mm.x ? 1.f : 0.f;
      vv.y = mm.y ? v.y : 0.f; mv.y = mm.y ? 1.f : 0.f;
      vv.z = mm.z ? v.z : 0.f; mv.z = mm.z ? 1.f : 0.f;
      vv.w = mm.w ? v.w : 0.f; mv.w = mm.w ? 1.f : 0.f;
      *(float4*)&nv[krow * 16 + c4 * 4] = vv;
      *(float4*)&nm[krow * 16 + c4 * 4] = mv;
    }
    __syncthreads();
#pragma unroll
    for (int kk = 0; kk < 64; ++kk) {
      const float ev = El[r * 68 + kk];
      const float2 v = *(const float2*)&nv[kk * 16 + cg * 2];
      const float2 mm = *(const float2*)&nm[kk * 16 + cg * 2];
      n0 += ev * v.x; n1 += ev * v.y;
      d0 += ev * mm.x; d1 += ev * mm.y;
    }
  }
  const int hq = rt * 32 + r;
  const int h = hq >> 6, q = hq & 63;
  const int xcol = h * 128 + ct * 16 + cg * 2;
  float2 xv;
  xv.x = n0 / d0;
  xv.y = n1 / d1;
  *(float2*)&x_ws[(size_t)(b * 64 + q) * 256 + xcol] = xv;
}

// ------------------------------------------------------------------
// K4: out = x @ Wout + bout.  32 blocks (b*4 + qt), 256 threads.
// Block: 16 q-rows x 64 out-cols, K=256 in 4 chunks of 64.
// ------------------------------------------------------------------
__global__ __launch_bounds__(256) void out_kernel(
    const float* __restrict__ x_ws, const float* __restrict__ Wout,
    const float* __restrict__ bout, float* __restrict__ out) {
  const int blk = blockIdx.x;
  const int b = blk >> 2, qt = blk & 3;
  __shared__ float xl[16 * 68];   // [16][64] pad->68
  __shared__ float wl[64 * 64];   // Wout chunk [64][64]
  const int tid = threadIdx.x;
  const int rloc = tid / 16, lg = tid % 16;

  float acc[4];
#pragma unroll
  for (int j = 0; j < 4; ++j) acc[j] = bout[lg * 4 + j];

  const float4* x4 = (const float4*)x_ws;
  const float4* W4 = (const float4*)Wout;
  for (int kc = 0; kc < 4; ++kc) {
    __syncthreads();
    // stage x tile: 16 rows x 64 k
    if (tid < 256) {
      const int row = tid >> 4, kq = tid & 15;
      float4 v = x4[((size_t)(b * 64 + qt * 16 + row) * 256 + kc * 64) / 4 + kq];
      *(float4*)&xl[row * 68 + kq * 4] = v;
    }
    // stage Wout chunk: 64 rows x 64 cols
    for (int i = tid; i < 1024; i += 256) {
      const int row = i >> 4, c4 = i & 15;
      float4 v = W4[(size_t)(kc * 64 + row) * 16 + c4];
      *(float4*)&wl[row * 64 + c4 * 4] = v;
    }
    __syncthreads();
#pragma unroll
    for (int kk = 0; kk < 64; ++kk) {
      const float xv = xl[rloc * 68 + kk];
      const float4 w = *(const float4*)&wl[kk * 64 + lg * 4];
      acc[0] += xv * w.x; acc[1] += xv * w.y;
      acc[2] += xv * w.z; acc[3] += xv * w.w;
    }
  }
  float4 o;
  o.x = acc[0]; o.y = acc[1]; o.z = acc[2]; o.w = acc[3];
  *(float4*)&out[(size_t)(b * 64 + qt * 16 + rloc) * 64 + lg * 4] = o;
}

extern "C" void kernel_launch(void* const* d_in, const int* in_sizes, int n_in,
                              void* d_out, int out_size, void* d_ws, size_t ws_size,
                              hipStream_t stream) {
  const float* query = (const float*)d_in[0];
  const float* key   = (const float*)d_in[1];
  const float* value = (const float*)d_in[2];
  const int*   mask  = (const int*)d_in[3];
  const float* Wq    = (const float*)d_in[4];
  const float* bq    = (const float*)d_in[5];
  const float* Wk    = (const float*)d_in[6];
  const float* bk    = (const float*)d_in[7];
  const float* Wout  = (const float*)d_in[8];
  const float* bout  = (const float*)d_in[9];
  float* out = (float*)d_out;

  float* ws = (float*)d_ws;
  float* qp = ws;                 // 8*64*32    = 16384
  float* kp = qp + 16384;         // 8*512*32   = 131072
  float* e  = kp + 131072;        // 8*2*64*512 = 524288
  float* xb = e + 524288;         // 8*64*256   = 131072

  proj_kernel<<<144, 256, 0, stream>>>(query, key, Wq, bq, Wk, bk, qp, kp);
  score_kernel<<<32, 256, 0, stream>>>(qp, kp, e);
  nd_kernel<<<256, 256, 0, stream>>>(e, value, mask, xb);
  out_kernel<<<32, 256, 0, stream>>>(xb, Wout, bout, out);
}